// Round 6
// baseline (143.572 us; speedup 1.0000x reference)
//
#include <hip/hip_runtime.h>
#include <hip/hip_bf16.h>
#include <math.h>

#define HS 64
#define NE 128
#define TSEQ 2048

typedef short s8v __attribute__((ext_vector_type(8)));   // 8 bf16 (4 VGPRs) MFMA A/B frag
typedef float f4v __attribute__((ext_vector_type(4)));   // 4 fp32 MFMA C/D frag

__device__ __forceinline__ unsigned short f2bf(float f) {
    unsigned int u = __float_as_uint(f);
    u += 0x7FFFu + ((u >> 16) & 1u);   // RNE (no NaN inputs here)
    return (unsigned short)(u >> 16);
}

// packed f32x2 -> bf16x2 (v_cvt_pk_bf16_f32 path via hip_bf16)
__device__ __forceinline__ unsigned int pkbf(float a, float b) {
    __hip_bfloat162 h = __float22bfloat162_rn(make_float2(a, b));
    union { __hip_bfloat162 h; unsigned int u; } cv;
    cv.h = h;
    return cv.u;
}

__device__ __forceinline__ s8v mk_s8v(unsigned int a, unsigned int b,
                                      unsigned int c, unsigned int d) {
    union { unsigned int u[4]; s8v v; } cv;
    cv.u[0] = a; cv.u[1] = b; cv.u[2] = c; cv.u[3] = d;
    return cv.v;
}

// ---------------- W -> bf16, transposed wt[mat][n][k], q pre-scaled ----------------
__global__ __launch_bounds__(256) void wconv(
    const float* __restrict__ Wq, const float* __restrict__ Wk,
    const float* __restrict__ Wv, unsigned short* __restrict__ wt)
{
    const int o0 = (blockIdx.x * 256 + threadIdx.x) * 2;   // 24576 elems total
    const int mat = o0 >> 13;
    const int n = (o0 >> 7) & 63;
    const int k = o0 & 127;        // even
    const float* W = (mat == 0) ? Wq : (mat == 1) ? Wk : Wv;
    const float s = (mat == 0) ? 0.18033688f : 1.0f;   // 64^-0.5 * log2(e)
    unsigned int lo = f2bf(W[k * HS + n] * s);
    unsigned int hi = f2bf(W[(k + 1) * HS + n] * s);
    *(unsigned int*)(wt + o0) = lo | (hi << 16);
}

// ---------------- QKV projection (bf16 MFMA, W in LDS, vector epilogue) -------------
// 512 blocks x 256 thr (4 waves); wave = 16 x-rows. q/k written row-major via
// fp32 LDS transpose (b128 stores); v written dim-major with packed uint2 stores.
__global__ __launch_bounds__(256) void qkv(
    const float* __restrict__ x, const unsigned short* __restrict__ wt,
    const float* __restrict__ bq, const float* __restrict__ bk,
    const float* __restrict__ bv,
    unsigned short* __restrict__ qo, unsigned short* __restrict__ ko,
    unsigned short* __restrict__ vt)
{
    __shared__ __align__(16) unsigned short Ws[192 * 136];  // 51 KB; reused for transpose

    const int tid = threadIdx.x;
    const int w = tid >> 6;
    const int lane = tid & 63;
    const int quad = lane >> 4;
    const int li = lane & 15;
    const size_t blk0 = (size_t)blockIdx.x * 64;
    const size_t row0w = blk0 + (size_t)w * 16;

    // stage W^T: 3072 8-elem chunks
#pragma unroll
    for (int p = 0; p < 12; ++p) {
        const int idx = p * 256 + tid;
        const int n = idx >> 4;
        const int c = idx & 15;
        s8v d = *(const s8v*)(wt + idx * 8);
        *(s8v*)&Ws[n * 136 + c * 8] = d;
    }

    // A-frags: 16 rows (m=li), k = quad*8+j
    s8v a[4];
    const float* xr = x + (row0w + li) * NE + quad * 8;
#pragma unroll
    for (int ks = 0; ks < 4; ++ks) {
        float4 f0 = *(const float4*)(xr + ks * 32);
        float4 f1 = *(const float4*)(xr + ks * 32 + 4);
        a[ks] = mk_s8v(pkbf(f0.x, f0.y), pkbf(f0.z, f0.w),
                       pkbf(f1.x, f1.y), pkbf(f1.z, f1.w));
    }

    __syncthreads();

    f4v acc[12];
#pragma unroll
    for (int nt = 0; nt < 12; ++nt) acc[nt] = (f4v){0.f, 0.f, 0.f, 0.f};

#pragma unroll
    for (int nt = 0; nt < 12; ++nt) {
        const unsigned short* wr = &Ws[(nt * 16 + li) * 136 + quad * 8];
#pragma unroll
        for (int ks = 0; ks < 4; ++ks) {
            s8v bfr = *(const s8v*)(wr + ks * 32);
            acc[nt] = __builtin_amdgcn_mfma_f32_16x16x32_bf16(a[ks], bfr, acc[nt], 0, 0, 0);
        }
    }

    // v epilogue: C rows (=t) consecutive per lane -> one 8B store per ntile
    const size_t bidx = row0w >> 11;
    const size_t trow0 = row0w & 2047;
#pragma unroll
    for (int nt = 0; nt < 4; ++nt) {
        const float bias = bv[nt * 16 + li];
        unsigned int lo = pkbf(acc[nt + 8][0] + bias, acc[nt + 8][1] + bias);
        unsigned int hi = pkbf(acc[nt + 8][2] + bias, acc[nt + 8][3] + bias);
        *(uint2*)(vt + (bidx * HS + nt * 16 + li) * TSEQ + trow0 + quad * 4) =
            make_uint2(lo, hi);
    }

    __syncthreads();   // all Ws reads done before reuse

    // q/k transpose through LDS (fp32, stride 68 -> 2-way banks = free)
    float* Qt = (float*)Ws;            // [64][68]
    float* Kt = Qt + 64 * 68;
    const float sq = 0.18033688f;
    const int lrow0 = w * 16 + quad * 4;
#pragma unroll
    for (int nt = 0; nt < 4; ++nt) {
        const int col = nt * 16 + li;
        const float bq_ = bq[col] * sq;
        const float bk_ = bk[col];
#pragma unroll
        for (int r = 0; r < 4; ++r) {
            Qt[(lrow0 + r) * 68 + col] = acc[nt][r] + bq_;
            Kt[(lrow0 + r) * 68 + col] = acc[nt + 4][r] + bk_;
        }
    }

    __syncthreads();

    const int row = tid >> 2;
    const int seg = tid & 3;
    {
        const float* src = &Qt[row * 68 + seg * 16];
        float4 f0 = *(const float4*)src;
        float4 f1 = *(const float4*)(src + 4);
        float4 f2 = *(const float4*)(src + 8);
        float4 f3 = *(const float4*)(src + 12);
        s8v d0 = mk_s8v(pkbf(f0.x, f0.y), pkbf(f0.z, f0.w), pkbf(f1.x, f1.y), pkbf(f1.z, f1.w));
        s8v d1 = mk_s8v(pkbf(f2.x, f2.y), pkbf(f2.z, f2.w), pkbf(f3.x, f3.y), pkbf(f3.z, f3.w));
        unsigned short* dst = qo + (blk0 + row) * HS + seg * 16;
        *(s8v*)dst = d0;
        *(s8v*)(dst + 8) = d1;
    }
    {
        const float* src = &Kt[row * 68 + seg * 16];
        float4 f0 = *(const float4*)src;
        float4 f1 = *(const float4*)(src + 4);
        float4 f2 = *(const float4*)(src + 8);
        float4 f3 = *(const float4*)(src + 12);
        s8v d0 = mk_s8v(pkbf(f0.x, f0.y), pkbf(f0.z, f0.w), pkbf(f1.x, f1.y), pkbf(f1.z, f1.w));
        s8v d1 = mk_s8v(pkbf(f2.x, f2.y), pkbf(f2.z, f2.w), pkbf(f3.x, f3.y), pkbf(f3.z, f3.w));
        unsigned short* dst = ko + (blk0 + row) * HS + seg * 16;
        *(s8v*)dst = d0;
        *(s8v*)(dst + 8) = d1;
    }
}

// ---------------- Flash attention (bf16 MFMA, barrier-free, reg-prefetched) --------
// 1024 blocks x 128 thr (2 waves). Wave tasks {a, 127-a} -> every block exactly
// 33 tile-iters (scheduler-proof balance). K/V frags direct from global
// (L1/L2-resident); K(t+1) prefetched into regs after S-MFMAs consume K(t);
// V(t) issued at iter top, lands during softmax. No __syncthreads anywhere.
__global__ __launch_bounds__(128) void attn(
    const unsigned short* __restrict__ qb,
    const unsigned short* __restrict__ kb,
    const unsigned short* __restrict__ vtb,
    float* __restrict__ out)
{
    __shared__ __align__(16) unsigned short Ps[2][16 * 72];

    const int tid = threadIdx.x;
    const int w = tid >> 6;
    const int lane = tid & 63;
    const int quad = lane >> 4;
    const int li = lane & 15;

    const int n = blockIdx.x;
    const int b = n >> 6;                 // sequential batches -> XCD L2 locality
    const int a = n & 63;
    const int qi = w ? (127 - a) : a;     // complementary pair inside the block
    const size_t base = (size_t)b * TSEQ;
    const int qrow = (qi << 4) + li;

    // Q B-frags (regs, once); scale*log2e pre-folded
    const unsigned short* qrp = qb + (base + qrow) * HS + quad * 8;
    s8v qf0 = *(const s8v*)qrp;
    s8v qf1 = *(const s8v*)(qrp + 32);

    const unsigned short* kl = kb + (base + li) * HS + quad * 8;
    const unsigned short* vl = vtb + ((size_t)b * HS + li) * TSEQ + quad * 8;

    const int nt64 = (qi >> 2) + 1;

    f4v c_o[4];
#pragma unroll
    for (int f = 0; f < 4; ++f) c_o[f] = (f4v){0.f, 0.f, 0.f, 0.f};
    float lsum = 0.f;

    unsigned short* prow = &Ps[w][li * 72];

    // preload K tile 0
    s8v kc0[4], kc1[4];
#pragma unroll
    for (int kt = 0; kt < 4; ++kt) {
        const unsigned short* p = kl + kt * 16 * HS;
        kc0[kt] = *(const s8v*)p;
        kc1[kt] = *(const s8v*)(p + 32);
    }

    for (int tl = 0; tl < nt64; ++tl) {
        const int s0 = tl << 6;
        const bool last = (tl == nt64 - 1);

        // V(t): issued now, consumed after softmax
        s8v vv0[4], vv1[4];
#pragma unroll
        for (int f = 0; f < 4; ++f) {
            const unsigned short* vp = vl + f * 16 * TSEQ + s0;
            vv0[f] = *(const s8v*)vp;
            vv1[f] = *(const s8v*)(vp + 32);
        }

        // S^T = K · Q^T (consumes kc)
        f4v cst[4];
#pragma unroll
        for (int kt = 0; kt < 4; ++kt) {
            f4v z = (f4v){0.f, 0.f, 0.f, 0.f};
            z = __builtin_amdgcn_mfma_f32_16x16x32_bf16(kc0[kt], qf0, z, 0, 0, 0);
            cst[kt] = __builtin_amdgcn_mfma_f32_16x16x32_bf16(kc1[kt], qf1, z, 0, 0, 0);
        }

        // K(t+1) register prefetch: overlaps softmax + PV + next-iter top
        if (tl + 1 < nt64) {
            const unsigned short* kn = kl + (size_t)(s0 + 64) * HS;
#pragma unroll
            for (int kt = 0; kt < 4; ++kt) {
                const unsigned short* p = kn + kt * 16 * HS;
                kc0[kt] = *(const s8v*)p;
                kc1[kt] = *(const s8v*)(p + 32);
            }
        }

        // softmax (exp2 domain, no max subtraction; causal mask on last tile)
        float pr[4][4];
        float rs = 0.f;
#pragma unroll
        for (int kt = 0; kt < 4; ++kt) {
            if (last) {
                const int key0 = s0 + kt * 16 + quad * 4;
#pragma unroll
                for (int rr = 0; rr < 4; ++rr)
                    if (key0 + rr > qrow) cst[kt][rr] = -INFINITY;
            }
#pragma unroll
            for (int rr = 0; rr < 4; ++rr) {
                pr[kt][rr] = exp2f(cst[kt][rr]);
                rs += pr[kt][rr];
            }
        }
        lsum += rs;   // per-lane partial; cross-quad reduced in epilogue

        // P -> LDS (wave-private; C-layout -> B-frag layout)
#pragma unroll
        for (int kt = 0; kt < 4; ++kt) {
            *(uint2*)(prow + kt * 16 + quad * 4) =
                make_uint2(pkbf(pr[kt][0], pr[kt][1]), pkbf(pr[kt][2], pr[kt][3]));
        }
        s8v pf0 = *(const s8v*)(prow + quad * 8);
        s8v pf1 = *(const s8v*)(prow + 32 + quad * 8);

        // O^T += V^T · P^T (waits vv only; kc prefetch stays in flight)
#pragma unroll
        for (int f = 0; f < 4; ++f) {
            c_o[f] = __builtin_amdgcn_mfma_f32_16x16x32_bf16(vv0[f], pf0, c_o[f], 0, 0, 0);
            c_o[f] = __builtin_amdgcn_mfma_f32_16x16x32_bf16(vv1[f], pf1, c_o[f], 0, 0, 0);
        }
    }

    lsum += __shfl_xor(lsum, 16);
    lsum += __shfl_xor(lsum, 32);
    const float inv = 1.0f / lsum;
    float* orow = out + (base + qrow) * HS + quad * 4;
#pragma unroll
    for (int f = 0; f < 4; ++f) {
        f4v res = c_o[f];
        res[0] *= inv; res[1] *= inv; res[2] *= inv; res[3] *= inv;
        *(f4v*)(orow + f * 16) = res;
    }
}

extern "C" void kernel_launch(void* const* d_in, const int* in_sizes, int n_in,
                              void* d_out, int out_size, void* d_ws, size_t ws_size,
                              hipStream_t stream) {
    const float* x  = (const float*)d_in[0];
    const float* Wk = (const float*)d_in[1];
    const float* bk = (const float*)d_in[2];
    const float* Wq = (const float*)d_in[3];
    const float* bq = (const float*)d_in[4];
    const float* Wv = (const float*)d_in[5];
    const float* bv = (const float*)d_in[6];
    float* outp = (float*)d_out;

    const size_t elems = (size_t)16 * TSEQ * HS;  // 2M per tensor
    unsigned short* qbuf = (unsigned short*)d_ws;
    unsigned short* kbuf = qbuf + elems;
    unsigned short* vbuf = kbuf + elems;          // transposed [b][dim][t]
    unsigned short* wtb  = vbuf + elems;          // [3][64][128] bf16

    wconv<<<48, 256, 0, stream>>>(Wq, Wk, Wv, wtb);
    qkv<<<512, 256, 0, stream>>>(x, wtb, bq, bk, bv, qbuf, kbuf, vbuf);
    attn<<<1024, 128, 0, stream>>>(qbuf, kbuf, vbuf, outp);
}